// Round 5
// baseline (10218.419 us; speedup 1.0000x reference)
//
#include <hip/hip_runtime.h>
#include <cstdint>
#include <cmath>

// Round-5: device-side dtype probe. Theory: inputs are FLOAT32 (per reference),
// not bf16 -- all prior NaN/zero failures trace to misreading f32 buffers as
// bf16. A probe kernel inspects x's 16-bit halves; a flag in ws selects f32 vs
// bf16 interpretation for all raw-input loads and for the d_out store dtype.
// Internal buffers (qkv, y) are always bf16. Scalar compute (correctness first).
//
// B=2, T=2048, D=2048, H=16, G=4, DK=128.
// ws: [128B flag block][qkv bf16 4096x3072][y bf16 4096x2048] ~= 42 MB.

typedef float f32;
constexpr int Tn = 2048;

// ---------------------------------------------------------------- dtype probe
// Scan 65536 16-bit halves of x. For true-bf16 N(0,1)-ish data the exponent
// field stays in (64,190) or is 0; for f32 data the even halves are random
// mantissa bits -> ~31% insane exponents (incl. 0xFF = NaN/Inf).
__global__ __launch_bounds__(256) void probe_dtype(const unsigned short* __restrict__ xbits,
                                                   int* __restrict__ flag) {
  __shared__ int red[256];
  const int tid = threadIdx.x;
  int cnt = 0;
  for (int i = tid; i < 65536; i += 256) {
    const int e = (xbits[i] >> 7) & 0xFF;
    if (e == 0xFF || (e != 0 && (e < 64 || e > 190))) ++cnt;
  }
  red[tid] = cnt;
  __syncthreads();
  for (int s = 128; s > 0; s >>= 1) {
    if (tid < s) red[tid] += red[tid + s];
    __syncthreads();
  }
  if (tid == 0) flag[0] = (red[0] > 256) ? 1 : 0;  // 1 => inputs are f32
}

__device__ __forceinline__ f32 load_in(const void* p, size_t idx, int isf32) {
  return isf32 ? ((const float*)p)[idx] : (f32)((const __bf16*)p)[idx];
}

// ---------------------------------------------------------------- GEMM
// C[M][Nc] = A[M][K] @ B[K][Nc]. 16x16 tile, 1 output/thread, fp32 LDS tiles.
// aF/bF/cF: operand participates in the f32-flag (raw input / output) or is
// fixed bf16 (internal buffer).
__global__ __launch_bounds__(256) void gemm_nn(const void* __restrict__ A,
                                               const void* __restrict__ B,
                                               void* __restrict__ C,
                                               int K, int ldb, int ldc,
                                               const int* __restrict__ flag,
                                               int aF, int bF, int cF) {
  const int f = flag[0];
  const int af = f & aF, bf2 = f & bF, cf = f & cF;
  __shared__ f32 As[16][17];
  __shared__ f32 Bs[16][17];
  const int tx = threadIdx.x, ty = threadIdx.y;
  const int row = blockIdx.y * 16 + ty;
  const int col = blockIdx.x * 16 + tx;
  f32 acc = 0.f;
  for (int k0 = 0; k0 < K; k0 += 16) {
    As[ty][tx] = load_in(A, (size_t)row * K + k0 + tx, af);
    Bs[ty][tx] = load_in(B, (size_t)(k0 + ty) * ldb + col, bf2);
    __syncthreads();
#pragma unroll
    for (int kk = 0; kk < 16; ++kk) acc += As[ty][kk] * Bs[kk][tx];
    __syncthreads();
  }
  if (cf)
    ((float*)C)[(size_t)row * ldc + col] = acc;
  else
    ((__bf16*)C)[(size_t)row * ldc + col] = (__bf16)acc;
}

// ---------------------------------------------------------------- RoPE
// qkv rows: 4096 (b*T+t), 3072 cols: Q = h*128+d, K = 2048+g*128+d, V untouched.
// pair (d, d+64), d<64; inv_freq = 10000^(-d/64); pos = t.
__global__ __launch_bounds__(256) void rope_kernel(__bf16* __restrict__ qkv) {
  const int row = blockIdx.x;
  const int t = row & (Tn - 1);
  for (int p = threadIdx.x; p < 1280; p += 256) {
    const int d = p & 63;
    const int hh = p >> 6;  // 0..15 Q heads, 16..19 K groups
    const int col = (hh < 16) ? (hh * 128 + d) : (2048 + (hh - 16) * 128 + d);
    const float inv = powf(10000.f, -(float)d * (1.0f / 64.f));
    const float ang = (float)t * inv;
    float sn, cs;
    sincosf(ang, &sn, &cs);
    __bf16* ptr = qkv + (size_t)row * 3072 + col;
    const float x1 = (float)ptr[0];
    const float x2 = (float)ptr[64];
    ptr[0] = (__bf16)(x1 * cs - x2 * sn);
    ptr[64] = (__bf16)(x2 * cs + x1 * sn);
  }
}

// ---------------------------------------------------------------- attention
// One wave per query row. Lane d holds dims d and d+64. Online softmax with
// full-wave butterfly reduction for the 128-dot-product.
__global__ __launch_bounds__(256) void attn_scalar(const __bf16* __restrict__ qkv,
                                                   __bf16* __restrict__ y) {
  const int b = blockIdx.y >> 4, h = blockIdx.y & 15;
  const int g = h >> 2;
  const int wave = threadIdx.x >> 6, lane = threadIdx.x & 63;
  const int t = blockIdx.x * 4 + wave;

  const __bf16* base = qkv + (size_t)b * Tn * 3072;
  const __bf16* qp = base + (size_t)t * 3072 + h * 128;
  const float q0 = (float)qp[lane];
  const float q1 = (float)qp[lane + 64];

  float m = -1e30f, l = 0.f, o0 = 0.f, o1 = 0.f;
  const float scale = 0.08838834764831845f;  // 1/sqrt(128)

  for (int j = 0; j <= t; ++j) {
    const __bf16* kp = base + (size_t)j * 3072 + 2048 + g * 128;
    float s = q0 * (float)kp[lane] + q1 * (float)kp[lane + 64];
    s += __shfl_xor(s, 1);
    s += __shfl_xor(s, 2);
    s += __shfl_xor(s, 4);
    s += __shfl_xor(s, 8);
    s += __shfl_xor(s, 16);
    s += __shfl_xor(s, 32);
    s *= scale;
    const float mn = fmaxf(m, s);
    const float p = __expf(s - mn);          // j==0: p=1
    const float alpha = __expf(m - mn);      // j==0: exp(-huge)=0
    const __bf16* vp = base + (size_t)j * 3072 + 2560 + g * 128;
    l = l * alpha + p;
    o0 = o0 * alpha + p * (float)vp[lane];
    o1 = o1 * alpha + p * (float)vp[lane + 64];
    m = mn;
  }

  __bf16* yp = y + (size_t)(b * Tn + t) * 2048 + h * 128;
  yp[lane] = (__bf16)(o0 / l);
  yp[lane + 64] = (__bf16)(o1 / l);
}

// ---------------------------------------------------------------- launch
extern "C" void kernel_launch(void* const* d_in, const int* in_sizes, int n_in,
                              void* d_out, int out_size, void* d_ws, size_t ws_size,
                              hipStream_t stream) {
  (void)in_sizes; (void)n_in; (void)out_size; (void)ws_size;
  const void* x  = d_in[0];
  const void* Wq = d_in[1];
  const void* Wk = d_in[2];
  const void* Wv = d_in[3];
  const void* Wo = d_in[4];
  // d_in[5] = mask (tril), d_in[6] = pos (arange) -- constants, recomputed inline.

  int*    flag = (int*)d_ws;
  __bf16* qkv  = (__bf16*)((char*)d_ws + 128);   // [4096][3072]
  __bf16* y    = qkv + (size_t)4096 * 3072;      // [4096][2048]

  probe_dtype<<<1, 256, 0, stream>>>((const unsigned short*)x, flag);

  dim3 blk(16, 16);
  // qkv columns: [0,2048) = x@Wq, [2048,2560) = x@Wk, [2560,3072) = x@Wv
  gemm_nn<<<dim3(2048 / 16, 4096 / 16), blk, 0, stream>>>(x, Wq, qkv,        2048, 2048, 3072, flag, 1, 1, 0);
  gemm_nn<<<dim3(512 / 16,  4096 / 16), blk, 0, stream>>>(x, Wk, qkv + 2048, 2048, 512,  3072, flag, 1, 1, 0);
  gemm_nn<<<dim3(512 / 16,  4096 / 16), blk, 0, stream>>>(x, Wv, qkv + 2560, 2048, 512,  3072, flag, 1, 1, 0);

  rope_kernel<<<4096, 256, 0, stream>>>(qkv);
  attn_scalar<<<dim3(Tn / 4, 2 * 16), 256, 0, stream>>>(qkv, y);

  // out = y @ Wo; store dtype follows the flag (f32 world -> f32 out).
  gemm_nn<<<dim3(2048 / 16, 4096 / 16), blk, 0, stream>>>(y, Wo, d_out, 2048, 2048, 2048, flag, 0, 1, 1);
}

// Round 6
// 593.652 us; speedup vs baseline: 17.2128x; 17.2128x over previous
//
#include <hip/hip_runtime.h>
#include <cstdint>
#include <cmath>

// Round-6: inputs CONFIRMED float32 (round-5 probe), output float32.
// MFMA pipeline: f32->bf16 convert/transpose front-ends, m97-style MFMA GEMMs
// (global_load_lds width=16), MFMA flash attention (round-2 design).
//
// B=2, T=2048, D=2048, H=16, G=4, DK=128.
// ws layout (54.6 MB):
//   [xb/y 4096x2048 bf16 16.8MB]  xb dead after gemm1 -> y aliases it
//   [WT 3072x2048 bf16 12.6MB]    WoT (2048x2048) aliases after gemm1
//   [qkv 4096x3072 bf16 25.2MB]

#define GLOBAL_AS __attribute__((address_space(1)))
#define LDS_AS __attribute__((address_space(3)))

typedef __bf16 bf16x8 __attribute__((ext_vector_type(8)));
typedef __bf16 bf16x4 __attribute__((ext_vector_type(4)));
typedef float f32x4 __attribute__((ext_vector_type(4)));

constexpr int Tn = 2048;

__device__ __forceinline__ f32x4 mfma_bf16(bf16x8 a, bf16x8 b, f32x4 c) {
  return __builtin_amdgcn_mfma_f32_16x16x32_bf16(a, b, c, 0, 0, 0);
}

// ---------------------------------------------------------------- convert f32 -> bf16
__global__ __launch_bounds__(256) void convert_f32_bf16(const float* __restrict__ src,
                                                        __bf16* __restrict__ dst,
                                                        size_t n4) {
  const size_t i = (size_t)blockIdx.x * 256 + threadIdx.x;
  if (i >= n4) return;
  const f32x4 v = ((const f32x4*)src)[i];
  bf16x4 o;
#pragma unroll
  for (int k = 0; k < 4; ++k) o[k] = (__bf16)v[k];
  ((bf16x4*)dst)[i] = o;
}

// ---------------------------------------------------------------- transpose+convert
// src f32: K rows x N cols -> dst bf16: N rows x K cols.
__global__ __launch_bounds__(256) void transpose_f32_bf16(const float* __restrict__ src,
                                                          __bf16* __restrict__ dst,
                                                          int K, int N) {
  __shared__ __bf16 tile[32][33];
  const int n0 = blockIdx.x * 32, k0 = blockIdx.y * 32;
  const int tx = threadIdx.x, ty = threadIdx.y;
#pragma unroll
  for (int i = 0; i < 32; i += 8)
    tile[ty + i][tx] = (__bf16)src[(size_t)(k0 + ty + i) * N + n0 + tx];
  __syncthreads();
#pragma unroll
  for (int i = 0; i < 32; i += 8)
    dst[(size_t)(n0 + ty + i) * K + k0 + tx] = tile[tx][ty + i];
}

// ---------------------------------------------------------------- GEMM (B^T)
// C[M][N] = A[M][K] @ BT[N][K]^T. 128x128 tile, BK=32, 4 waves (2x2 of 64x64),
// global_load_lds width=16 staging, 16x16x32 bf16 MFMA. outf32: C is float*.
__global__ __launch_bounds__(256) void gemm_bt(const __bf16* __restrict__ A,
                                               const __bf16* __restrict__ BT,
                                               void* __restrict__ C,
                                               int K, int ldc, int outf32) {
  __shared__ __attribute__((aligned(16))) __bf16 As[128 * 32];
  __shared__ __attribute__((aligned(16))) __bf16 Bs[128 * 32];
  const int tid = threadIdx.x;
  const int wave = tid >> 6, lane = tid & 63;
  const int lr = lane & 15, lq = lane >> 4;
  const int wm = wave >> 1, wn = wave & 1;
  const int m0 = blockIdx.y * 128, n0 = blockIdx.x * 128;

  f32x4 acc[4][4] = {};

  // staging: lane (tid) covers row (it*64 + tid>>2), cols (tid&3)*8 .. +8
  const int srow = tid >> 2;
  const int scol = (tid & 3) * 8;
  const __bf16* ga = A + (size_t)(m0 + srow) * K + scol;
  const __bf16* gb = BT + (size_t)(n0 + srow) * K + scol;

  for (int kt = 0; kt < K; kt += 32) {
    __syncthreads();
#pragma unroll
    for (int it = 0; it < 2; ++it) {
      __builtin_amdgcn_global_load_lds((GLOBAL_AS void*)(ga + (size_t)it * 64 * K + kt),
                                       (LDS_AS void*)(As + it * 2048 + wave * 512), 16, 0, 0);
      __builtin_amdgcn_global_load_lds((GLOBAL_AS void*)(gb + (size_t)it * 64 * K + kt),
                                       (LDS_AS void*)(Bs + it * 2048 + wave * 512), 16, 0, 0);
    }
    __syncthreads();  // vmcnt(0) drained before barrier -> tiles ready

    bf16x8 af[4], bfv[4];
#pragma unroll
    for (int i = 0; i < 4; ++i)
      af[i] = *(const bf16x8*)(As + (wm * 64 + i * 16 + lr) * 32 + lq * 8);
#pragma unroll
    for (int j = 0; j < 4; ++j)
      bfv[j] = *(const bf16x8*)(Bs + (wn * 64 + j * 16 + lr) * 32 + lq * 8);
#pragma unroll
    for (int i = 0; i < 4; ++i)
#pragma unroll
      for (int j = 0; j < 4; ++j)
        acc[i][j] = mfma_bf16(af[i], bfv[j], acc[i][j]);
  }

#pragma unroll
  for (int i = 0; i < 4; ++i) {
    const int row = m0 + wm * 64 + i * 16 + lq * 4;
#pragma unroll
    for (int j = 0; j < 4; ++j) {
      const int col = n0 + wn * 64 + j * 16 + lr;
#pragma unroll
      for (int r = 0; r < 4; ++r) {
        if (outf32)
          ((float*)C)[(size_t)(row + r) * ldc + col] = acc[i][j][r];
        else
          ((__bf16*)C)[(size_t)(row + r) * ldc + col] = (__bf16)acc[i][j][r];
      }
    }
  }
}

// ---------------------------------------------------------------- RoPE
// qkv rows: 4096 (b*T+t), 3072 cols: Q = h*128+d, K = 2048+g*128+d, V untouched.
// pair (d, d+64), d<64; inv_freq = 10000^(-d/64); pos = t.
__global__ __launch_bounds__(256) void rope_kernel(__bf16* __restrict__ qkv) {
  const int row = blockIdx.x;
  const int t = row & (Tn - 1);
  for (int p = threadIdx.x; p < 1280; p += 256) {
    const int d = p & 63;
    const int hh = p >> 6;  // 0..15 Q heads, 16..19 K groups
    const int col = (hh < 16) ? (hh * 128 + d) : (2048 + (hh - 16) * 128 + d);
    // inv_freq = 10000^(-d/64) = exp2(-d * log2(10000)/64)
    const float inv = exp2f((float)d * (-13.287712379549449f / 64.f));
    const float ang = (float)t * inv;
    float sn, cs;
    __sincosf(ang, &sn, &cs);
    __bf16* ptr = qkv + (size_t)row * 3072 + col;
    const float x1 = (float)ptr[0];
    const float x2 = (float)ptr[64];
    ptr[0] = (__bf16)(x1 * cs - x2 * sn);
    ptr[64] = (__bf16)(x2 * cs + x1 * sn);
  }
}

// ---------------------------------------------------------------- flash attention
// grid: (T/64, B*H). 4 waves/block, wave w owns Q rows q0+w*16..+16.
// 32-key tiles; V^T staged in LDS (shared); P via fenced LDS round-trip.
__global__ __launch_bounds__(256) void flash_attn(const __bf16* __restrict__ qkv,
                                                  __bf16* __restrict__ y) {
  const int b = blockIdx.y >> 4, h = blockIdx.y & 15;
  const int g = h >> 2;  // rf = 4
  const int q0 = blockIdx.x * 64;
  const int tid = threadIdx.x;
  const int wave = tid >> 6, lane = tid & 63;
  const int lr = lane & 15, lq = lane >> 4;

  const __bf16* Qb = qkv + (size_t)b * Tn * 3072 + h * 128;
  const __bf16* Kb = qkv + (size_t)b * Tn * 3072 + 2048 + g * 128;
  const __bf16* Vb = qkv + (size_t)b * Tn * 3072 + 2560 + g * 128;

  __shared__ __attribute__((aligned(16))) __bf16 Vt[128 * 32];   // [dim][key]
  __shared__ __attribute__((aligned(16))) __bf16 Pl[4][16 * 32]; // per-wave [qrow][key]

  // Q tile, A-operand layout: frag f = dims f*32 + lq*8 .. +8, row lr
  const int qrow = q0 + wave * 16 + lr;
  bf16x8 qf[4];
#pragma unroll
  for (int f = 0; f < 4; ++f)
    qf[f] = *(const bf16x8*)(Qb + (size_t)qrow * 3072 + f * 32 + lq * 8);

  f32x4 o[8] = {};     // O accumulator, C-layout, 8 dim-slices of 16
  float m_i[4], l_i[4];
#pragma unroll
  for (int r = 0; r < 4; ++r) { m_i[r] = -1e30f; l_i[r] = 0.f; }
  const float scale = 0.08838834764831845f;  // 1/sqrt(128)

  const int vkey = tid >> 3;
  const int vd0 = (tid & 7) * 16;

  for (int kt = 0; kt < q0 + 64; kt += 32) {
    __syncthreads();  // prev-iter Vt/Pl reads done before overwrite
    {   // stage V^T: 32 keys x 128 dims -> Vt[dim*32+key]
      const __bf16* vp = Vb + (size_t)(kt + vkey) * 3072 + vd0;
      bf16x8 v0 = *(const bf16x8*)vp;
      bf16x8 v1 = *(const bf16x8*)(vp + 8);
#pragma unroll
      for (int i = 0; i < 8; ++i) {
        Vt[(vd0 + i) * 32 + vkey] = v0[i];
        Vt[(vd0 + 8 + i) * 32 + vkey] = v1[i];
      }
    }
    __syncthreads();

    // S = Q K^T : two 16-key tiles
    f32x4 s0 = {}, s1 = {};
#pragma unroll
    for (int f = 0; f < 4; ++f) {
      bf16x8 kf = *(const bf16x8*)(Kb + (size_t)(kt + lr) * 3072 + f * 32 + lq * 8);
      s0 = mfma_bf16(qf[f], kf, s0);
    }
#pragma unroll
    for (int f = 0; f < 4; ++f) {
      bf16x8 kf = *(const bf16x8*)(Kb + (size_t)(kt + 16 + lr) * 3072 + f * 32 + lq * 8);
      s1 = mfma_bf16(qf[f], kf, s1);
    }

    // online softmax per row (row lq*4+r, key cols lr / lr+16)
#pragma unroll
    for (int r = 0; r < 4; ++r) {
      const int q = q0 + wave * 16 + lq * 4 + r;
      const bool v0ok = (kt + lr) <= q;
      const bool v1ok = (kt + 16 + lr) <= q;
      float a0 = v0ok ? s0[r] * scale : -1e30f;
      float a1 = v1ok ? s1[r] * scale : -1e30f;
      float mx = fmaxf(a0, a1);
      mx = fmaxf(mx, __shfl_xor(mx, 1));
      mx = fmaxf(mx, __shfl_xor(mx, 2));
      mx = fmaxf(mx, __shfl_xor(mx, 4));
      mx = fmaxf(mx, __shfl_xor(mx, 8));
      const float mnew = fmaxf(m_i[r], mx);
      const float p0 = v0ok ? __expf(a0 - mnew) : 0.f;
      const float p1 = v1ok ? __expf(a1 - mnew) : 0.f;
      float rs = p0 + p1;
      rs += __shfl_xor(rs, 1);
      rs += __shfl_xor(rs, 2);
      rs += __shfl_xor(rs, 4);
      rs += __shfl_xor(rs, 8);
      const float alpha = __expf(m_i[r] - mnew);
      m_i[r] = mnew;
      l_i[r] = l_i[r] * alpha + rs;
#pragma unroll
      for (int n = 0; n < 8; ++n) o[n][r] *= alpha;
      Pl[wave][(lq * 4 + r) * 32 + lr] = (__bf16)p0;
      Pl[wave][(lq * 4 + r) * 32 + 16 + lr] = (__bf16)p1;
    }

    __syncthreads();  // fence Pl writes (scalar) vs reads (vector)

    // P (C-layout) -> A-layout frag; PV accumulate
    bf16x8 pa = *(const bf16x8*)(&Pl[wave][lr * 32 + lq * 8]);
#pragma unroll
    for (int n = 0; n < 8; ++n) {
      bf16x8 vv = *(const bf16x8*)(&Vt[(n * 16 + lr) * 32 + lq * 8]);
      o[n] = mfma_bf16(pa, vv, o[n]);
    }
  }

#pragma unroll
  for (int r = 0; r < 4; ++r) {
    const int q = q0 + wave * 16 + lq * 4 + r;
    const float inv = 1.0f / l_i[r];
#pragma unroll
    for (int n = 0; n < 8; ++n)
      y[(size_t)(b * Tn + q) * 2048 + h * 128 + n * 16 + lr] = (__bf16)(o[n][r] * inv);
  }
}

// ---------------------------------------------------------------- launch
extern "C" void kernel_launch(void* const* d_in, const int* in_sizes, int n_in,
                              void* d_out, int out_size, void* d_ws, size_t ws_size,
                              hipStream_t stream) {
  (void)in_sizes; (void)n_in; (void)out_size; (void)ws_size;
  const float* x  = (const float*)d_in[0];
  const float* Wq = (const float*)d_in[1];
  const float* Wk = (const float*)d_in[2];
  const float* Wv = (const float*)d_in[3];
  const float* Wo = (const float*)d_in[4];
  // d_in[5] = mask (tril), d_in[6] = pos (arange) -- constants, recomputed inline.
  float* out = (float*)d_out;

  __bf16* xb  = (__bf16*)d_ws;                  // [4096][2048]; y aliases after gemm1
  __bf16* y   = xb;
  __bf16* WT  = xb + (size_t)4096 * 2048;       // [3072][2048]; WoT aliases after gemm1
  __bf16* WoT = WT;
  __bf16* qkv = WT + (size_t)3072 * 2048;       // [4096][3072]

  // f32 -> bf16 convert x; transpose+convert Wq|Wk|Wv -> WT
  convert_f32_bf16<<<(4096 * 2048 / 4 + 255) / 256, 256, 0, stream>>>(x, xb, 4096 * 2048 / 4);
  dim3 tb(32, 8);
  transpose_f32_bf16<<<dim3(64, 64), tb, 0, stream>>>(Wq, WT, 2048, 2048);
  transpose_f32_bf16<<<dim3(16, 64), tb, 0, stream>>>(Wk, WT + (size_t)2048 * 2048, 2048, 512);
  transpose_f32_bf16<<<dim3(16, 64), tb, 0, stream>>>(Wv, WT + (size_t)2560 * 2048, 2048, 512);

  gemm_bt<<<dim3(3072 / 128, 4096 / 128), 256, 0, stream>>>(xb, WT, qkv, 2048, 3072, 0);
  rope_kernel<<<4096, 256, 0, stream>>>(qkv);
  flash_attn<<<dim3(Tn / 64, 2 * 16), 256, 0, stream>>>(qkv, y);

  transpose_f32_bf16<<<dim3(64, 64), tb, 0, stream>>>(Wo, WoT, 2048, 2048);
  gemm_bt<<<dim3(2048 / 128, 4096 / 128), 256, 0, stream>>>(y, WoT, out, 2048, 2048, 1);
}